// Round 10
// baseline (315.630 us; speedup 1.0000x reference)
//
#include <hip/hip_runtime.h>
#include <math.h>

// ---------------------------------------------------------------------------
// GIN network on MI355X — round 10.
//  - Layer fully fused: gather (sum-aggregate) writes the MFMA A-tile in LDS
//    directly (swizzled), then GEMM1+ReLU+GEMM2(+ReLU / fc tail) in the same
//    block. Kills the Z round-trip (51 MB/layer) + 3 launches.
//    512 thr = 8 waves; 64x8-lane gather groups pull nodes from an LDS
//    atomic counter; col window LDS-staged; 6-deep x 2-chunk pipeline.
//    2 blocks/CU (74.6 KB LDS) -> gather of one block overlaps GEMM of the
//    other. GEMM = 16 rows/wave.
//  - CSR two-level binning unchanged. Gather FETCH (~172 MB/layer) is at the
//    compulsory cross-XCD duplication floor; this round removes overhead.
// ---------------------------------------------------------------------------

using f16   = _Float16;
using f16x4 = __attribute__((ext_vector_type(4))) _Float16;
using f16x8 = __attribute__((ext_vector_type(8))) _Float16;
using f32x4 = __attribute__((ext_vector_type(4))) float;

constexpr int BINBLK = 256;   // binning grid (blocks); count matrix columns

__device__ inline void glds16(const void* g, void* l) {
    __builtin_amdgcn_global_load_lds(
        (const __attribute__((address_space(1))) void*)g,
        (__attribute__((address_space(3))) void*)l, 16, 0, 0);
}

// ---------------- CSR build: two-level binning ----------------
// bucket = dst >> 8  (256 nodes per bucket)

__global__ __launch_bounds__(512) void bucket_count_kernel(const int* __restrict__ dst,
                                                           int* __restrict__ cntM,
                                                           int E, int nbuck) {
    __shared__ int cnt[512];
    for (int i = threadIdx.x; i < nbuck; i += 512) cnt[i] = 0;
    __syncthreads();
    int chunk = (E + gridDim.x - 1) / gridDim.x;
    int lo = blockIdx.x * chunk, hi = min(lo + chunk, E);
    for (int e = lo + threadIdx.x; e < hi; e += 512)
        atomicAdd(&cnt[dst[e] >> 8], 1);
    __syncthreads();
    for (int i = threadIdx.x; i < nbuck; i += 512)
        cntM[(size_t)i * gridDim.x + blockIdx.x] = cnt[i];
}

__global__ __launch_bounds__(256) void scan_partial(const int* __restrict__ deg,
                                                    int* __restrict__ bsum, int n) {
    __shared__ int red[256];
    int b = blockIdx.x, t = threadIdx.x;
    int base = b * 1024;
    int s = 0;
#pragma unroll
    for (int j = 0; j < 4; ++j) {
        int idx = base + j * 256 + t;
        if (idx < n) s += deg[idx];
    }
    red[t] = s;
    __syncthreads();
    for (int d = 128; d > 0; d >>= 1) {
        if (t < d) red[t] += red[t + d];
        __syncthreads();
    }
    if (t == 0) bsum[b] = red[0];
}

__global__ __launch_bounds__(128) void scan_bsum(const int* __restrict__ bsum,
                                                 int* __restrict__ bbase, int nb,
                                                 int* __restrict__ total_out) {
    __shared__ int s[128];
    int t = threadIdx.x;
    s[t] = (t < nb) ? bsum[t] : 0;
    __syncthreads();
    for (int d = 1; d < 128; d <<= 1) {
        int v = (t >= d) ? s[t - d] : 0;
        __syncthreads();
        s[t] += v;
        __syncthreads();
    }
    bbase[t] = (t > 0) ? s[t - 1] : 0;
    if (t == 127) total_out[0] = s[127];
}

__global__ __launch_bounds__(256) void scan_final(const int* __restrict__ deg,
                                                  const int* __restrict__ bbase,
                                                  int* __restrict__ outA,
                                                  int* __restrict__ outB, int n) {
    __shared__ int red[256];
    int b = blockIdx.x, t = threadIdx.x;
    int base = b * 1024 + t * 4;
    int d0 = 0, d1 = 0, d2 = 0, d3 = 0;
    if (base + 3 < n) {
        int4 v = *(const int4*)&deg[base];
        d0 = v.x; d1 = v.y; d2 = v.z; d3 = v.w;
    } else {
        if (base < n) d0 = deg[base];
        if (base + 1 < n) d1 = deg[base + 1];
        if (base + 2 < n) d2 = deg[base + 2];
    }
    red[t] = d0 + d1 + d2 + d3;
    __syncthreads();
    for (int d = 1; d < 256; d <<= 1) {
        int v = (t >= d) ? red[t - d] : 0;
        __syncthreads();
        red[t] += v;
        __syncthreads();
    }
    int ex = bbase[b] + ((t > 0) ? red[t - 1] : 0);
    int o0 = ex, o1 = ex + d0, o2 = o1 + d1, o3 = o2 + d2;
    if (base + 3 < n) {
        *(int4*)&outA[base] = make_int4(o0, o1, o2, o3);
        *(int4*)&outB[base] = make_int4(o0, o1, o2, o3);
    } else {
        if (base < n) { outA[base] = o0; outB[base] = o0; }
        if (base + 1 < n) { outA[base + 1] = o1; outB[base + 1] = o1; }
        if (base + 2 < n) { outA[base + 2] = o2; outB[base + 2] = o2; }
    }
}

__global__ __launch_bounds__(512) void bin_kernel(const int* __restrict__ src,
                                                  const int* __restrict__ dst,
                                                  const int* __restrict__ baseM,
                                                  int2* __restrict__ stage, int E, int nbuck) {
    __shared__ int cur[512];
    for (int i = threadIdx.x; i < nbuck; i += 512)
        cur[i] = baseM[(size_t)i * gridDim.x + blockIdx.x];
    __syncthreads();
    int chunk = (E + gridDim.x - 1) / gridDim.x;
    int lo = blockIdx.x * chunk, hi = min(lo + chunk, E);
    for (int e = lo + threadIdx.x; e < hi; e += 512) {
        int d = dst[e];
        int p = atomicAdd(&cur[d >> 8], 1);
        stage[p] = make_int2(src[e], d);
    }
}

__global__ __launch_bounds__(256) void csr_kernel(const int2* __restrict__ stage,
                                                  const int* __restrict__ baseM,
                                                  int* __restrict__ offs,
                                                  int* __restrict__ col,
                                                  int E, int N, int nbuck, int binblk) {
    constexpr int CAP = 10240;
    __shared__ int cnt[256];
    __shared__ int sc[256];
    __shared__ int colbuf[CAP];
    int b = blockIdx.x, t = threadIdx.x;
    int base = baseM[(size_t)b * binblk];
    int end = (b + 1 < nbuck) ? baseM[(size_t)(b + 1) * binblk] : E;
    cnt[t] = 0;
    __syncthreads();
    for (int e = base + t; e < end; e += 256)
        atomicAdd(&cnt[stage[e].y & 255], 1);
    __syncthreads();
    int myCnt = cnt[t];
    sc[t] = myCnt;
    __syncthreads();
    for (int d = 1; d < 256; d <<= 1) {
        int u = (t >= d) ? sc[t - d] : 0;
        __syncthreads();
        sc[t] += u;
        __syncthreads();
    }
    int myExcl = sc[t] - myCnt;
    int node = b * 256 + t;
    if (node <= N) offs[node] = base + myExcl;
    cnt[t] = myExcl;  // reuse as cursor
    __syncthreads();
    for (int e = base + t; e < end; e += 256) {
        int2 sd = stage[e];
        int p = atomicAdd(&cnt[sd.y & 255], 1);
        if (p < CAP) colbuf[p] = sd.x;
        else col[base + p] = sd.x;
    }
    __syncthreads();
    int lim = min(end - base, CAP);
    for (int i = t; i < lim; i += 256) col[base + i] = colbuf[i];
}

// ---------------- fp32 -> f16 conversions ----------------
__global__ void cvt4_kernel(const float* __restrict__ in, f16* __restrict__ out, int nq) {
    int stride = gridDim.x * blockDim.x;
    for (int i = blockIdx.x * blockDim.x + threadIdx.x; i < nq; i += stride) {
        float4 v = *(const float4*)(in + (size_t)i * 4);
        f16x4 o = {(f16)v.x, (f16)v.y, (f16)v.z, (f16)v.w};
        *(f16x4*)(out + (size_t)i * 4) = o;
    }
}

struct CvtPack {
    const float* s[7];
    f16* d[7];
    int nq[7];
};
__global__ void cvt_pack_kernel(CvtPack p) {
    int seg = blockIdx.y;
    int nq = p.nq[seg];
    const float* in = p.s[seg];
    f16* out = p.d[seg];
    int stride = gridDim.x * blockDim.x;
    for (int i = blockIdx.x * blockDim.x + threadIdx.x; i < nq; i += stride) {
        float4 v = *(const float4*)(in + (size_t)i * 4);
        f16x4 o = {(f16)v.x, (f16)v.y, (f16)v.z, (f16)v.w};
        *(f16x4*)(out + (size_t)i * 4) = o;
    }
}

// ---------------- fused GIN layer ----------------
// Block = 128 nodes. Phase 1: gather z = (1+eps)h + sum h[nbr] directly into
// swizzled A-tile in LDS (64 groups x 8 lanes, dynamic node pull via LDS
// counter, col window LDS-staged, 6-deep x 2-chunk pipeline). Phase 2:
// GEMM1+ReLU -> As (swizzled), restage W2, GEMM2. !LAST: +b2,ReLU -> Hout.
// LAST: fc1+ReLU+fc2+sigmoid tail (Red aliases the col pool).
template <bool LAST>
__global__ __launch_bounds__(512, 4) void conv_fused_kernel(
    const f16* __restrict__ H, const int* __restrict__ offs,
    const int* __restrict__ col, const float* __restrict__ epsp,
    const f16* __restrict__ W1f, const float* __restrict__ b1,
    const f16* __restrict__ W2f, const float* __restrict__ b2,
    f16* __restrict__ Hout, int M,
    const f16* __restrict__ fc1wf, const float* __restrict__ fc1b,
    const float* __restrict__ fc2w, const float* __restrict__ fc2b,
    float* __restrict__ out) {
    constexpr int COLCAP = 2560;  // mean window 2048, +11 sigma
    __shared__ __align__(16) f16 As[128 * 128];
    __shared__ __align__(16) f16 Ws[128 * 128];
    __shared__ __align__(16) int poolB[COLCAP + 132];
    int* colLDS = poolB;
    int* sOffs = poolB + COLCAP;        // 129 entries
    int* ctr = poolB + COLCAP + 130;
    float* Red = (float*)poolB;         // LAST tail only (colLDS dead by then)

    const int tid = threadIdx.x;
    const int w = tid >> 6, lane = tid & 63;
    const int frow = lane & 15, kgrp = lane >> 4;
    const int m0 = blockIdx.x * 128;
    const int u = lane & 15, rsub = lane >> 4;

    // stage W1 (pre-swizzled global source)
#pragma unroll
    for (int i = 0; i < 4; ++i) {
        int rowbase = (w * 4 + i) * 4;
        int r = rowbase + rsub;
        glds16(W1f + (size_t)r * 128 + ((u ^ (r & 7)) << 3), &Ws[rowbase * 128]);
    }
    for (int i = tid; i < 129; i += 512) sOffs[i] = offs[min(m0 + i, M)];
    if (tid == 0) *ctr = 0;
    __syncthreads();
    const int cbase = sOffs[0];
    const int wlen = sOffs[128] - cbase;
    const bool useLds = wlen <= COLCAP;
    if (useLds)
        for (int i = tid; i < wlen; i += 512)
            colLDS[i] = __builtin_nontemporal_load(&col[cbase + i]);
    __syncthreads();

    // ---- gather phase ----
    {
        const int li = tid & 7;
        const int gbase = lane & ~7;  // group leader lane in wave
        const f16x8* hp = (const f16x8*)H;  // row = 16 f16x8
        const float e1 = 1.0f + epsp[0];
        for (;;) {
            int n = 0;
            if (li == 0) n = atomicAdd(ctr, 1);
            n = __shfl(n, gbase, 64);
            if (n >= 128) break;
            const int coA = li, coB = li + 8;
            f16* dstA = &As[n * 128 + ((coA ^ (n & 7)) << 3)];
            f16* dstB = &As[n * 128 + ((coB ^ (n & 7)) << 3)];
            const int node = m0 + n;
            if (node >= M) {
                f16x8 zz = {};
                *(f16x8*)dstA = zz;
                *(f16x8*)dstB = zz;
                continue;
            }
            f16x8 sA = hp[(size_t)node * 16 + coA];
            f16x8 sB = hp[(size_t)node * 16 + coB];
            float a[8], b[8];
#pragma unroll
            for (int c = 0; c < 8; ++c) {
                a[c] = (float)sA[c] * e1;
                b[c] = (float)sB[c] * e1;
            }
            int lo = sOffs[n] - cbase, hi = sOffs[n + 1] - cbase;
            int e = lo;
            for (; e + 6 <= hi; e += 6) {
                int idx[6];
#pragma unroll
                for (int j = 0; j < 6; ++j)
                    idx[j] = useLds ? colLDS[e + j] : col[cbase + e + j];
                f16x8 vA[6], vB[6];
#pragma unroll
                for (int j = 0; j < 6; ++j) {
                    vA[j] = hp[(size_t)idx[j] * 16 + coA];
                    vB[j] = hp[(size_t)idx[j] * 16 + coB];
                }
#pragma unroll
                for (int j = 0; j < 6; ++j)
#pragma unroll
                    for (int c = 0; c < 8; ++c) {
                        a[c] += (float)vA[j][c];
                        b[c] += (float)vB[j][c];
                    }
            }
            for (; e < hi; ++e) {
                int idx = useLds ? colLDS[e] : col[cbase + e];
                f16x8 vA = hp[(size_t)idx * 16 + coA];
                f16x8 vB = hp[(size_t)idx * 16 + coB];
#pragma unroll
                for (int c = 0; c < 8; ++c) {
                    a[c] += (float)vA[c];
                    b[c] += (float)vB[c];
                }
            }
            f16x8 oA, oB;
#pragma unroll
            for (int c = 0; c < 8; ++c) {
                oA[c] = (f16)a[c];
                oB[c] = (f16)b[c];
            }
            *(f16x8*)dstA = oA;
            *(f16x8*)dstB = oB;
        }
    }
    __syncthreads();

    // ---- GEMM1: 16 rows per wave ----
    const int arow0 = w * 16 + frow;
    f32x4 acc[8];
#pragma unroll
    for (int nj = 0; nj < 8; ++nj) acc[nj] = (f32x4){0.f, 0.f, 0.f, 0.f};
#pragma unroll
    for (int kk = 0; kk < 4; ++kk) {
        int kb = kk * 4 + kgrp;
        f16x8 a = *(const f16x8*)&As[arow0 * 128 + ((kb ^ (arow0 & 7)) << 3)];
        f16x8 b[8];
#pragma unroll
        for (int nj = 0; nj < 8; ++nj) {
            int r = nj * 16 + frow;
            b[nj] = *(const f16x8*)&Ws[r * 128 + ((kb ^ (r & 7)) << 3)];
        }
#pragma unroll
        for (int nj = 0; nj < 8; ++nj)
            acc[nj] = __builtin_amdgcn_mfma_f32_16x16x32_f16(a, b[nj], acc[nj], 0, 0, 0);
    }
    __syncthreads();

    // restage W2 while epilogue writes As
#pragma unroll
    for (int i = 0; i < 4; ++i) {
        int rowbase = (w * 4 + i) * 4;
        int r = rowbase + rsub;
        glds16(W2f + (size_t)r * 128 + ((u ^ (r & 7)) << 3), &Ws[rowbase * 128]);
    }
    {
        float bv[8];
#pragma unroll
        for (int nj = 0; nj < 8; ++nj) bv[nj] = b1[nj * 16 + frow];
        const int row0 = w * 16 + kgrp * 4;
#pragma unroll
        for (int nj = 0; nj < 8; ++nj) {
            int c = nj * 16 + frow;
            int cu = c >> 3, cl = c & 7;
#pragma unroll
            for (int r = 0; r < 4; ++r) {
                int rr = row0 + r;
                As[rr * 128 + ((cu ^ (rr & 7)) << 3) + cl] =
                    (f16)fmaxf(acc[nj][r] + bv[nj], 0.f);
            }
        }
    }
    __syncthreads();

    // ---- GEMM2 ----
#pragma unroll
    for (int nj = 0; nj < 8; ++nj) acc[nj] = (f32x4){0.f, 0.f, 0.f, 0.f};
#pragma unroll
    for (int kk = 0; kk < 4; ++kk) {
        int kb = kk * 4 + kgrp;
        f16x8 a = *(const f16x8*)&As[arow0 * 128 + ((kb ^ (arow0 & 7)) << 3)];
        f16x8 b[8];
#pragma unroll
        for (int nj = 0; nj < 8; ++nj) {
            int r = nj * 16 + frow;
            b[nj] = *(const f16x8*)&Ws[r * 128 + ((kb ^ (r & 7)) << 3)];
        }
#pragma unroll
        for (int nj = 0; nj < 8; ++nj)
            acc[nj] = __builtin_amdgcn_mfma_f32_16x16x32_f16(a, b[nj], acc[nj], 0, 0, 0);
    }
    float bv2[8];
#pragma unroll
    for (int nj = 0; nj < 8; ++nj) bv2[nj] = b2[nj * 16 + frow];

    if (!LAST) {
        __syncthreads();
        const int row0 = w * 16 + kgrp * 4;
#pragma unroll
        for (int nj = 0; nj < 8; ++nj) {
            int c = nj * 16 + frow;
#pragma unroll
            for (int r = 0; r < 4; ++r)
                As[(row0 + r) * 128 + c] = (f16)fmaxf(acc[nj][r] + bv2[nj], 0.f);
        }
        __syncthreads();
        for (int idx = tid; idx < 128 * 16; idx += 512) {
            int r = idx >> 4, q = idx & 15;
            int gm = m0 + r;
            if (gm < M)
                *(float4*)(Hout + (size_t)gm * 128 + q * 8) = *(const float4*)&As[r * 128 + q * 8];
        }
    } else {
        __syncthreads();
        // stage fc1w (64 rows)
#pragma unroll
        for (int i = 0; i < 2; ++i) {
            int rowbase = (w * 2 + i) * 4;
            int r = rowbase + rsub;
            glds16(fc1wf + (size_t)r * 128 + ((u ^ (r & 7)) << 3), &Ws[rowbase * 128]);
        }
        const int row0 = w * 16 + kgrp * 4;
#pragma unroll
        for (int nj = 0; nj < 8; ++nj) {
            int c = nj * 16 + frow;
            int cu = c >> 3, cl = c & 7;
#pragma unroll
            for (int r = 0; r < 4; ++r) {
                int rr = row0 + r;
                As[rr * 128 + ((cu ^ (rr & 7)) << 3) + cl] =
                    (f16)fmaxf(acc[nj][r] + bv2[nj], 0.f);
            }
        }
        __syncthreads();

        // GEMM3: h @ fc1^T (64 cols)
        f32x4 acc3[4];
#pragma unroll
        for (int nj = 0; nj < 4; ++nj) acc3[nj] = (f32x4){0.f, 0.f, 0.f, 0.f};
#pragma unroll
        for (int kk = 0; kk < 4; ++kk) {
            int kb = kk * 4 + kgrp;
            f16x8 a = *(const f16x8*)&As[arow0 * 128 + ((kb ^ (arow0 & 7)) << 3)];
            f16x8 b[4];
#pragma unroll
            for (int nj = 0; nj < 4; ++nj) {
                int r = nj * 16 + frow;
                b[nj] = *(const f16x8*)&Ws[r * 128 + ((kb ^ (r & 7)) << 3)];
            }
#pragma unroll
            for (int nj = 0; nj < 4; ++nj)
                acc3[nj] = __builtin_amdgcn_mfma_f32_16x16x32_f16(a, b[nj], acc3[nj], 0, 0, 0);
        }
        float bvf[4], f2[4];
#pragma unroll
        for (int nj = 0; nj < 4; ++nj) {
            bvf[nj] = fc1b[nj * 16 + frow];
            f2[nj] = fc2w[nj * 16 + frow];
        }
        float part[4] = {0.f, 0.f, 0.f, 0.f};
#pragma unroll
        for (int nj = 0; nj < 4; ++nj)
#pragma unroll
            for (int r = 0; r < 4; ++r)
                part[r] += fmaxf(acc3[nj][r] + bvf[nj], 0.f) * f2[nj];
#pragma unroll
        for (int r = 0; r < 4; ++r) Red[(row0 + r) * 17 + frow] = part[r];
        __syncthreads();
        if (tid < 128) {
            float s = fc2b[0];
#pragma unroll
            for (int q = 0; q < 16; ++q) s += Red[tid * 17 + q];
            int m = m0 + tid;
            if (m < M) out[m] = 1.f / (1.f + expf(-s));
        }
    }
}

// ---------------------------------------------------------------------------
extern "C" void kernel_launch(void* const* d_in, const int* in_sizes, int n_in,
                              void* d_out, int out_size, void* d_ws, size_t ws_size,
                              hipStream_t stream) {
    const float* x = (const float*)d_in[0];
    const int* ei = (const int*)d_in[1];
    const int N = in_sizes[0] / 128;
    const int E = in_sizes[1] / 2;
    const int* srcIdx = ei;
    const int* dstIdx = ei + E;

    const float* w1[3] = {(const float*)d_in[2], (const float*)d_in[7], (const float*)d_in[12]};
    const float* b1[3] = {(const float*)d_in[3], (const float*)d_in[8], (const float*)d_in[13]};
    const float* w2[3] = {(const float*)d_in[4], (const float*)d_in[9], (const float*)d_in[14]};
    const float* b2[3] = {(const float*)d_in[5], (const float*)d_in[10], (const float*)d_in[15]};
    const float* eps[3] = {(const float*)d_in[6], (const float*)d_in[11], (const float*)d_in[16]};
    const float* fc1w = (const float*)d_in[17];
    const float* fc1b = (const float*)d_in[18];
    const float* fc2w = (const float*)d_in[19];
    const float* fc2b = (const float*)d_in[20];

    // workspace carve
    char* ws = (char*)d_ws;
    size_t p = 0;
    auto carve = [&](size_t bytes) -> char* {
        char* r = ws + p;
        p = (p + bytes + 255) & ~(size_t)255;
        return r;
    };
    const int nbuck = (N + 255) >> 8;          // 256-node buckets
    const int nm = nbuck * BINBLK;             // count-matrix size
    int* offs = (int*)carve((size_t)(N + 1) * 4);
    int* col = (int*)carve((size_t)E * 4);
    int* cntM = (int*)carve((size_t)nm * 4);
    int* baseM = (int*)carve((size_t)nm * 4);
    int* baseM2 = (int*)carve((size_t)nm * 4);  // scan scratch (unused copy)
    int* bsum = (int*)carve(128 * 4);
    int* bbase = (int*)carve(128 * 4);
    int* tot = (int*)carve(4);
    int2* stage = (int2*)carve((size_t)E * 8);
    f16* H0 = (f16*)carve((size_t)N * 128 * 2);
    f16* H1 = (f16*)carve((size_t)N * 128 * 2);
    f16* w1f[3], *w2f[3];
    for (int i = 0; i < 3; ++i) {
        w1f[i] = (f16*)carve(128 * 128 * 2);
        w2f[i] = (f16*)carve(128 * 128 * 2);
    }
    f16* fc1wf = (f16*)carve(64 * 128 * 2);
    (void)ws_size;

    // ---- build CSR (deterministic two-level binning) ----
    const int SB2 = (nm + 1023) / 1024;  // <=128 for nbuck*256 <= 128K
    bucket_count_kernel<<<BINBLK, 512, 0, stream>>>(dstIdx, cntM, E, nbuck);
    scan_partial<<<SB2, 256, 0, stream>>>(cntM, bsum, nm);
    scan_bsum<<<1, 128, 0, stream>>>(bsum, bbase, SB2, tot);
    scan_final<<<SB2, 256, 0, stream>>>(cntM, bbase, baseM, baseM2, nm);
    bin_kernel<<<BINBLK, 512, 0, stream>>>(srcIdx, dstIdx, baseM, stage, E, nbuck);
    csr_kernel<<<nbuck, 256, 0, stream>>>(stage, baseM, offs, col, E, N, nbuck, BINBLK);

    // ---- fp32 -> f16: x and all MFMA weights ----
    cvt4_kernel<<<2048, 256, 0, stream>>>(x, H0, N * 128 / 4);
    CvtPack cp;
    for (int i = 0; i < 3; ++i) {
        cp.s[i] = w1[i];     cp.d[i] = w1f[i];     cp.nq[i] = 128 * 128 / 4;
        cp.s[3 + i] = w2[i]; cp.d[3 + i] = w2f[i]; cp.nq[3 + i] = 128 * 128 / 4;
    }
    cp.s[6] = fc1w; cp.d[6] = fc1wf; cp.nq[6] = 64 * 128 / 4;
    cvt_pack_kernel<<<dim3(16, 7), 256, 0, stream>>>(cp);

    const int gemmGrid = (N + 127) / 128;

    // conv0: H0 -> H1 ; conv1: H1 -> H0 ; conv2+fc: H0 -> out
    conv_fused_kernel<false><<<gemmGrid, 512, 0, stream>>>(
        H0, offs, col, eps[0], w1f[0], b1[0], w2f[0], b2[0], H1, N,
        nullptr, nullptr, nullptr, nullptr, nullptr);
    conv_fused_kernel<false><<<gemmGrid, 512, 0, stream>>>(
        H1, offs, col, eps[1], w1f[1], b1[1], w2f[1], b2[1], H0, N,
        nullptr, nullptr, nullptr, nullptr, nullptr);
    conv_fused_kernel<true><<<gemmGrid, 512, 0, stream>>>(
        H0, offs, col, eps[2], w1f[2], b1[2], w2f[2], b2[2], nullptr, N,
        fc1wf, fc1b, fc2w, fc2b, (float*)d_out);
}